// Round 1
// 1922.912 us; speedup vs baseline: 1.2104x; 1.2104x over previous
//
#include <hip/hip_runtime.h>

typedef _Float16 half2v __attribute__((ext_vector_type(2)));
typedef _Float16 half8 __attribute__((ext_vector_type(8)));
typedef float floatx4 __attribute__((ext_vector_type(4)));

#define T_LEN 2048

// LDS-only barrier: waits ds ops, does NOT drain vmcnt (globals stay in flight)
#define LDS_BARRIER() asm volatile("s_waitcnt lgkmcnt(0)\n\ts_barrier" ::: "memory")

#if __has_builtin(__builtin_amdgcn_fdot2)
#define FDOT2(a, b, c) __builtin_amdgcn_fdot2((a), (b), (c), false)
#else
static __device__ inline float fdot2_fallback(half2v a, half2v b, float c) {
    return fmaf((float)a[1], (float)b[1], fmaf((float)a[0], (float)b[0], c));
}
#define FDOT2(a, b, c) fdot2_fallback((a), (b), (c))
#endif

// ---------------- Kernel 1: fused per-token table + Wh cast ----------------
__global__ __launch_bounds__(256) void precompute_k(
    const float* __restrict__ E, const float* __restrict__ Wx,
    const float* __restrict__ Wh, const float* __restrict__ Wz,
    float2* __restrict__ wgt, _Float16* __restrict__ Whf)
{
    const int v = blockIdx.x, e = threadIdx.x;
    __shared__ float Ev[256];
    Ev[e] = E[v * 256 + e];
    __syncthreads();
    float ax = 0.f, az = 0.f;
    #pragma unroll 4
    for (int d = 0; d < 256; d += 4) {
        float4 ev = *(const float4*)&Ev[d];
        float4 wx = *(const float4*)&Wx[e * 256 + d];
        float4 wz = *(const float4*)&Wz[e * 256 + d];
        ax += ev.x * wx.x + ev.y * wx.y + ev.z * wx.z + ev.w * wx.w;
        az += ev.x * wz.x + ev.y * wz.y + ev.z * wz.z + ev.w * wz.w;
    }
    float2 o; o.x = ax; o.y = 1.f / (1.f + __expf(-az));
    wgt[v * 256 + e] = o;
    Whf[v * 256 + e] = (_Float16)Wh[v * 256 + e];
}

// ---------------- Kernel 2: the serial recurrence (batch-parallel dot2) ----
// Batches are independent -> spread across 64 CUs instead of 4.
// 32 WGs x 2 batches; 512 threads = 8 waves (2/SIMD); waves 0-3 = batch-half
// 0, waves 4-7 = batch-half 1 (independent chains amortize barrier stalls).
// Within a batch: 4 waves x 64 lanes = 256 lanes. Wave w owns output dims
// [64w, 64w+64). Lane l: g = l&15, kq = l>>4. Dot phase: lane computes
// partial dots for dims dbase..dbase+3 over k in [64kq, 64kq+64) with
// v_dot2_f32_f16 against Wh rows held in 128 VGPRs (loaded once). 2-round
// __shfl_xor(16,32) completes the sums; lane kq finishes dim dbase+kq:
// tanh epilogue, gated y-store, f16 h write to LDS (padded k-quarters ->
// conflict-free broadcast reads). One LDS-only barrier per step; wgt row
// gather prefetched 2 steps ahead directly into the consumed registers.
__global__ __launch_bounds__(512, 2) void rnn_k(
    const int* __restrict__ tokens, const float2* __restrict__ wgt,
    const _Float16* __restrict__ Whf, float* __restrict__ y)
{
    const int tid = threadIdx.x;
    const int bh  = tid >> 8;                 // batch half within WG
    const int w   = (tid >> 6) & 3;           // wave within half
    const int l   = tid & 63;
    const int g   = l & 15, kq = l >> 4;
    const int b   = (blockIdx.x << 1) + bh;   // global batch
    const int dbase = (w << 6) + (g << 2);    // first of 4 dims this lane dots
    const int k0    = kq << 6;                // k-range start (64 wide)
    const int dout  = dbase + kq;             // dim this lane finishes

    // Wh fragments in registers: wh[j][c] = Wh[dbase+j][k0+8c .. k0+8c+7]
    union HW { half8 v; half2v p[4]; };
    HW wh[4][8];
    #pragma unroll
    for (int j = 0; j < 4; ++j)
        #pragma unroll
        for (int c = 0; c < 8; ++c)
            wh[j][c].v = *(const half8*)(Whf + (dbase + j) * 256 + k0 + (c << 3));

    // h double-buffered per batch-half; k-quarters padded 64->72 f16 (144 B)
    // so the 4 kq broadcast-read groups land on disjoint banks.
    __shared__ __align__(16) _Float16 hb[2][2][4][72];
    __shared__ unsigned char tokL[2][T_LEN];

    for (int i = tid; i < 2 * T_LEN; i += 512) {
        const int hh = i >> 11, t = i & (T_LEN - 1);
        tokL[hh][t] = (unsigned char)tokens[((blockIdx.x << 1) + hh) * T_LEN + t];
    }
    for (int i = tid; i < 2 * 2 * 4 * 72; i += 512) ((_Float16*)hb)[i] = (_Float16)0.f;
    LDS_BARRIER();

    // y byte offset: ((b*T + t)*256 + dout)*4, advances 1024 B per step
    unsigned int yoff = (unsigned)(b * (T_LEN * 256) + dout) * 4u;

    // prologue: wx/gate for t=0 (even regs) and t=1 (odd regs)
    float wx_e, g_e, wx_o, g_o;
    {
        const int t0 = tokL[bh][0], t1 = tokL[bh][1];
        float2 a = wgt[t0 * 256 + dout]; wx_e = a.x; g_e = a.y;
        float2 c = wgt[t1 * 256 + dout]; wx_o = c.x; g_o = c.y;
    }

// One timestep. Reads hb[bh][CUR] (h_{t-1}), writes hb[bh][NXT] (h_t).
// Consumes WX/G, then refills them IN PLACE for tcur+2 (first consumer two
// barriers later -> L2 gather latency fully covered).
#define STEP(tcur, CUR, NXT, WX, G)                                            \
    {                                                                          \
        int tf = (tcur) + 2; if (tf > T_LEN - 1) tf = T_LEN - 1;               \
        const int tok = tokL[bh][tf];                                          \
        float ac0 = 0.f, ac1 = 0.f, ac2 = 0.f, ac3 = 0.f;                      \
        _Pragma("unroll")                                                      \
        for (int c = 0; c < 8; ++c) {                                          \
            HW hv;                                                             \
            hv.v = *(const half8*)&hb[bh][CUR][kq][c << 3];                    \
            _Pragma("unroll")                                                  \
            for (int p = 0; p < 4; ++p) {                                      \
                ac0 = FDOT2(wh[0][c].p[p], hv.p[p], ac0);                      \
                ac1 = FDOT2(wh[1][c].p[p], hv.p[p], ac1);                      \
                ac2 = FDOT2(wh[2][c].p[p], hv.p[p], ac2);                      \
                ac3 = FDOT2(wh[3][c].p[p], hv.p[p], ac3);                      \
            }                                                                  \
        }                                                                      \
        ac0 += __shfl_xor(ac0, 16); ac0 += __shfl_xor(ac0, 32);                \
        ac1 += __shfl_xor(ac1, 16); ac1 += __shfl_xor(ac1, 32);                \
        ac2 += __shfl_xor(ac2, 16); ac2 += __shfl_xor(ac2, 32);                \
        ac3 += __shfl_xor(ac3, 16); ac3 += __shfl_xor(ac3, 32);                \
        float s01 = (kq & 1) ? ac1 : ac0;                                      \
        float s23 = (kq & 1) ? ac3 : ac2;                                      \
        float sv  = (kq & 2) ? s23 : s01;                                      \
        float pre = sv + WX;                                                   \
        float ex  = __builtin_amdgcn_exp2f(pre * 2.885390082f);                \
        float hval = fmaf(__builtin_amdgcn_rcpf(ex + 1.f), -2.f, 1.f);         \
        __builtin_nontemporal_store(hval * G, (float*)((char*)y + yoff));      \
        yoff += 1024;                                                          \
        hb[bh][NXT][w][(g << 2) + kq] = (_Float16)hval;                        \
        { const float2* gp = wgt + tok * 256 + dout; float2 a = *gp;           \
          WX = a.x; G = a.y; }                                                 \
        LDS_BARRIER();                                                         \
    }

    for (int t = 0; t < T_LEN; t += 2) {
        STEP(t,     0, 1, wx_e, g_e)   // even: h_{t-1} in buf0, h_t -> buf1
        STEP(t + 1, 1, 0, wx_o, g_o)   // odd:  h_t in buf1, h_{t+1} -> buf0
    }
#undef STEP
}

// ---------------- Kernel 3: tied head, in place ----------------
__device__ inline half8 cvt8(const float* p) {
    float4 u = *(const float4*)p;
    float4 w = *(const float4*)(p + 4);
    half8 r;
    r[0] = (_Float16)u.x; r[1] = (_Float16)u.y; r[2] = (_Float16)u.z; r[3] = (_Float16)u.w;
    r[4] = (_Float16)w.x; r[5] = (_Float16)w.y; r[6] = (_Float16)w.z; r[7] = (_Float16)w.w;
    return r;
}

__global__ __launch_bounds__(256) void logits_k(
    const float* __restrict__ E, float* __restrict__ io)
{
    const int tid = threadIdx.x;
    const int wv = tid >> 6;             // v-chunk base = wv*64
    const int l  = tid & 63;
    const int n  = l & 15, q = l >> 4;
    const int rowbase = blockIdx.x << 6; // 64 rows per WG
    const int k0base = q << 3;

    floatx4 acc[4][4];
    #pragma unroll
    for (int mt = 0; mt < 4; ++mt)
        #pragma unroll
        for (int tn = 0; tn < 4; ++tn) acc[mt][tn] = 0.f;

    #pragma unroll
    for (int ks = 0; ks < 8; ++ks) {
        const int k0 = (ks << 5) + k0base;
        half8 a[4], bfr[4];
        #pragma unroll
        for (int mt = 0; mt < 4; ++mt)
            a[mt] = cvt8(io + (rowbase + (mt << 4) + n) * 256 + k0);
        #pragma unroll
        for (int tn = 0; tn < 4; ++tn)
            bfr[tn] = cvt8(E + ((wv << 6) + (tn << 4) + n) * 256 + k0);
        #pragma unroll
        for (int mt = 0; mt < 4; ++mt)
            #pragma unroll
            for (int tn = 0; tn < 4; ++tn)
                acc[mt][tn] = __builtin_amdgcn_mfma_f32_16x16x32_f16(a[mt], bfr[tn], acc[mt][tn], 0, 0, 0);
    }
    __syncthreads();  // every wave's y reads complete before anyone overwrites
    #pragma unroll
    for (int mt = 0; mt < 4; ++mt)
        #pragma unroll
        for (int tn = 0; tn < 4; ++tn)
            #pragma unroll
            for (int r = 0; r < 4; ++r)
                io[(rowbase + (mt << 4) + (q << 2) + r) * 256 + (wv << 6) + (tn << 4) + n] = acc[mt][tn][r];
}

// ---------------- host ----------------
extern "C" void kernel_launch(void* const* d_in, const int* in_sizes, int n_in,
                              void* d_out, int out_size, void* d_ws, size_t ws_size,
                              hipStream_t stream) {
    const int*   tokens = (const int*)d_in[0];
    const float* E      = (const float*)d_in[1];
    const float* Wx     = (const float*)d_in[2];
    const float* Wh     = (const float*)d_in[3];
    const float* Wz     = (const float*)d_in[4];
    float* out = (float*)d_out;

    char* ws = (char*)d_ws;
    float2*   wgt = (float2*)ws;                      // 512 KiB
    _Float16* Whf = (_Float16*)(ws + (512 << 10));    // 128 KiB

    precompute_k<<<256, 256, 0, stream>>>(E, Wx, Wh, Wz, wgt, Whf);
    rnn_k<<<32, 512, 0, stream>>>(tokens, wgt, Whf, out);
    logits_k<<<2048, 256, 0, stream>>>(E, out);
}

// Round 7
// 1401.746 us; speedup vs baseline: 1.6604x; 1.3718x over previous
//
#include <hip/hip_runtime.h>

typedef _Float16 half2v __attribute__((ext_vector_type(2)));
typedef _Float16 half8 __attribute__((ext_vector_type(8)));
typedef float floatx4 __attribute__((ext_vector_type(4)));

#define T_LEN 2048

// LDS-only barrier: waits ds ops, does NOT drain vmcnt (globals stay in flight)
#define LDS_BARRIER() asm volatile("s_waitcnt lgkmcnt(0)\n\ts_barrier" ::: "memory")

#if __has_builtin(__builtin_amdgcn_fdot2)
#define FDOT2(a, b, c) __builtin_amdgcn_fdot2((a), (b), (c), false)
#else
static __device__ inline float fdot2_fallback(half2v a, half2v b, float c) {
    return fmaf((float)a[1], (float)b[1], fmaf((float)a[0], (float)b[0], c));
}
#define FDOT2(a, b, c) fdot2_fallback((a), (b), (c))
#endif

// ---------------- Kernel 1: fused per-token table + Wh cast ----------------
__global__ __launch_bounds__(256) void precompute_k(
    const float* __restrict__ E, const float* __restrict__ Wx,
    const float* __restrict__ Wh, const float* __restrict__ Wz,
    float2* __restrict__ wgt, _Float16* __restrict__ Whf)
{
    const int v = blockIdx.x, e = threadIdx.x;
    __shared__ float Ev[256];
    Ev[e] = E[v * 256 + e];
    __syncthreads();
    float ax = 0.f, az = 0.f;
    #pragma unroll 4
    for (int d = 0; d < 256; d += 4) {
        float4 ev = *(const float4*)&Ev[d];
        float4 wx = *(const float4*)&Wx[e * 256 + d];
        float4 wz = *(const float4*)&Wz[e * 256 + d];
        ax += ev.x * wx.x + ev.y * wx.y + ev.z * wx.z + ev.w * wx.w;
        az += ev.x * wz.x + ev.y * wz.y + ev.z * wz.z + ev.w * wz.w;
    }
    float2 o; o.x = ax; o.y = 1.f / (1.f + __expf(-az));
    wgt[v * 256 + e] = o;
    Whf[v * 256 + e] = (_Float16)Wh[v * 256 + e];
}

// ---------------- Kernel 2: the serial recurrence (batch-per-WG dot2) -----
// 64 WGs x 1 batch, 256 threads (4 waves, 1/SIMD). Private barrier per batch
// -> independent chains never couple. Wave w owns output dims [64w, 64w+64).
// Lane l: g = l&15, kq = l>>4. Lane computes partial dots for dims
// dbase..dbase+3 over k in [64kq, 64kq+64) with v_dot2_f32_f16 against Wh
// rows held REGISTER-RESIDENT (half8 array; pair extraction via
// __builtin_shufflevector with LITERAL indices -> free sub-register aliasing,
// no union/memory access, so the 128 Wh VGPRs stay pinned). 2-round
// __shfl_xor(16,32) completes the sums; each lane finishes dim dbase+kq:
// tanh epilogue, gated y-store, f16 h write to LDS (padded k-quarters ->
// conflict-free broadcast reads). One LDS-only barrier per step; wgt row
// gather prefetched 2 steps ahead directly into the consumed registers.
__global__ __launch_bounds__(256, 1) void rnn_k(
    const int* __restrict__ tokens, const float2* __restrict__ wgt,
    const _Float16* __restrict__ Whf, float* __restrict__ y)
{
    const int tid = threadIdx.x;
    const int w   = tid >> 6;                 // wave = output-dim chunk
    const int l   = tid & 63;
    const int g   = l & 15, kq = l >> 4;
    const int b   = blockIdx.x;               // global batch
    const int dbase = (w << 6) + (g << 2);    // first of 4 dims this lane dots
    const int k0    = kq << 6;                // k-range start (64 wide)
    const int dout  = dbase + kq;             // dim this lane finishes

    // Wh fragments in registers: wh8[j][c] = Wh[dbase+j][k0+8c .. k0+8c+7]
    half8 wh8[4][8];
    #pragma unroll
    for (int j = 0; j < 4; ++j)
        #pragma unroll
        for (int c = 0; c < 8; ++c)
            wh8[j][c] = *(const half8*)(Whf + (dbase + j) * 256 + k0 + (c << 3));

    // h double-buffered; k-quarters padded 64->72 f16 (144 B) so the 4 kq
    // broadcast-read groups land on disjoint banks.
    __shared__ __align__(16) _Float16 hb[2][4][72];
    __shared__ unsigned char tokL[T_LEN];

    for (int i = tid; i < T_LEN; i += 256)
        tokL[i] = (unsigned char)tokens[b * T_LEN + i];
    for (int i = tid; i < 2 * 4 * 72; i += 256) ((_Float16*)hb)[i] = (_Float16)0.f;
    LDS_BARRIER();

    // y byte offset: ((b*T + t)*256 + dout)*4, advances 1024 B per step
    unsigned int yoff = (unsigned)(b * (T_LEN * 256) + dout) * 4u;

    // prologue: wx/gate for t=0 (even regs) and t=1 (odd regs)
    float wx_e, g_e, wx_o, g_o;
    {
        const int t0 = tokL[0], t1 = tokL[1];
        float2 a = wgt[t0 * 256 + dout]; wx_e = a.x; g_e = a.y;
        float2 c = wgt[t1 * 256 + dout]; wx_o = c.x; g_o = c.y;
    }

// one k-pair (literal lane indices I0,I1 of the half8) against all 4 dims
#define DOT_P(cc, I0, I1)                                                      \
        {                                                                      \
            half2v hp = __builtin_shufflevector(hv, hv, I0, I1);               \
            ac0 = FDOT2(__builtin_shufflevector(wh8[0][cc], wh8[0][cc], I0, I1), hp, ac0); \
            ac1 = FDOT2(__builtin_shufflevector(wh8[1][cc], wh8[1][cc], I0, I1), hp, ac1); \
            ac2 = FDOT2(__builtin_shufflevector(wh8[2][cc], wh8[2][cc], I0, I1), hp, ac2); \
            ac3 = FDOT2(__builtin_shufflevector(wh8[3][cc], wh8[3][cc], I0, I1), hp, ac3); \
        }

// One timestep. Reads hb[CUR] (h_{t-1}), writes hb[NXT] (h_t). Consumes WX/G,
// then refills them IN PLACE for tcur+2 (first consumer two barriers later
// -> L2 gather latency fully covered).
#define STEP(tcur, CUR, NXT, WX, G)                                            \
    {                                                                          \
        int tf = (tcur) + 2; if (tf > T_LEN - 1) tf = T_LEN - 1;               \
        const int tok = tokL[tf];                                              \
        float ac0 = 0.f, ac1 = 0.f, ac2 = 0.f, ac3 = 0.f;                      \
        _Pragma("unroll")                                                      \
        for (int c = 0; c < 8; ++c) {                                          \
            half8 hv = *(const half8*)&hb[CUR][kq][c << 3];                    \
            DOT_P(c, 0, 1) DOT_P(c, 2, 3) DOT_P(c, 4, 5) DOT_P(c, 6, 7)        \
        }                                                                      \
        ac0 += __shfl_xor(ac0, 16); ac0 += __shfl_xor(ac0, 32);                \
        ac1 += __shfl_xor(ac1, 16); ac1 += __shfl_xor(ac1, 32);                \
        ac2 += __shfl_xor(ac2, 16); ac2 += __shfl_xor(ac2, 32);                \
        ac3 += __shfl_xor(ac3, 16); ac3 += __shfl_xor(ac3, 32);                \
        float s01 = (kq & 1) ? ac1 : ac0;                                      \
        float s23 = (kq & 1) ? ac3 : ac2;                                      \
        float sv  = (kq & 2) ? s23 : s01;                                      \
        float pre = sv + WX;                                                   \
        float ex  = __builtin_amdgcn_exp2f(pre * 2.885390082f);                \
        float hval = fmaf(__builtin_amdgcn_rcpf(ex + 1.f), -2.f, 1.f);         \
        __builtin_nontemporal_store(hval * G, (float*)((char*)y + yoff));      \
        yoff += 1024;                                                          \
        hb[NXT][w][(g << 2) + kq] = (_Float16)hval;                            \
        { const float2* gp = wgt + tok * 256 + dout; float2 a = *gp;           \
          WX = a.x; G = a.y; }                                                 \
        LDS_BARRIER();                                                         \
    }

    for (int t = 0; t < T_LEN; t += 2) {
        STEP(t,     0, 1, wx_e, g_e)   // even: h_{t-1} in buf0, h_t -> buf1
        STEP(t + 1, 1, 0, wx_o, g_o)   // odd:  h_t in buf1, h_{t+1} -> buf0
    }
#undef STEP
#undef DOT_P
}

// ---------------- Kernel 3: tied head, in place ----------------
__device__ inline half8 cvt8(const float* p) {
    float4 u = *(const float4*)p;
    float4 w = *(const float4*)(p + 4);
    half8 r;
    r[0] = (_Float16)u.x; r[1] = (_Float16)u.y; r[2] = (_Float16)u.z; r[3] = (_Float16)u.w;
    r[4] = (_Float16)w.x; r[5] = (_Float16)w.y; r[6] = (_Float16)w.z; r[7] = (_Float16)w.w;
    return r;
}

__global__ __launch_bounds__(256) void logits_k(
    const float* __restrict__ E, float* __restrict__ io)
{
    const int tid = threadIdx.x;
    const int wv = tid >> 6;             // v-chunk base = wv*64
    const int l  = tid & 63;
    const int n  = l & 15, q = l >> 4;
    const int rowbase = blockIdx.x << 6; // 64 rows per WG
    const int k0base = q << 3;

    floatx4 acc[4][4];
    #pragma unroll
    for (int mt = 0; mt < 4; ++mt)
        #pragma unroll
        for (int tn = 0; tn < 4; ++tn) acc[mt][tn] = 0.f;

    #pragma unroll
    for (int ks = 0; ks < 8; ++ks) {
        const int k0 = (ks << 5) + k0base;
        half8 a[4], bfr[4];
        #pragma unroll
        for (int mt = 0; mt < 4; ++mt)
            a[mt] = cvt8(io + (rowbase + (mt << 4) + n) * 256 + k0);
        #pragma unroll
        for (int tn = 0; tn < 4; ++tn)
            bfr[tn] = cvt8(E + ((wv << 6) + (tn << 4) + n) * 256 + k0);
        #pragma unroll
        for (int mt = 0; mt < 4; ++mt)
            #pragma unroll
            for (int tn = 0; tn < 4; ++tn)
                acc[mt][tn] = __builtin_amdgcn_mfma_f32_16x16x32_f16(a[mt], bfr[tn], acc[mt][tn], 0, 0, 0);
    }
    __syncthreads();  // every wave's y reads complete before anyone overwrites
    #pragma unroll
    for (int mt = 0; mt < 4; ++mt)
        #pragma unroll
        for (int tn = 0; tn < 4; ++tn)
            #pragma unroll
            for (int r = 0; r < 4; ++r)
                io[(rowbase + (mt << 4) + (q << 2) + r) * 256 + (wv << 6) + (tn << 4) + n] = acc[mt][tn][r];
}

// ---------------- host ----------------
extern "C" void kernel_launch(void* const* d_in, const int* in_sizes, int n_in,
                              void* d_out, int out_size, void* d_ws, size_t ws_size,
                              hipStream_t stream) {
    const int*   tokens = (const int*)d_in[0];
    const float* E      = (const float*)d_in[1];
    const float* Wx     = (const float*)d_in[2];
    const float* Wh     = (const float*)d_in[3];
    const float* Wz     = (const float*)d_in[4];
    float* out = (float*)d_out;

    char* ws = (char*)d_ws;
    float2*   wgt = (float2*)ws;                      // 512 KiB
    _Float16* Whf = (_Float16*)(ws + (512 << 10));    // 128 KiB

    precompute_k<<<256, 256, 0, stream>>>(E, Wx, Wh, Wz, wgt, Whf);
    rnn_k<<<64, 256, 0, stream>>>(tokens, wgt, Whf, out);
    logits_k<<<2048, 256, 0, stream>>>(E, out);
}

// Round 8
// 1392.605 us; speedup vs baseline: 1.6713x; 1.0066x over previous
//
#include <hip/hip_runtime.h>

typedef _Float16 half2v __attribute__((ext_vector_type(2)));
typedef _Float16 half8 __attribute__((ext_vector_type(8)));
typedef float floatx4 __attribute__((ext_vector_type(4)));

#define T_LEN 2048

// LDS-only barrier: waits ds ops, does NOT drain vmcnt (globals stay in flight)
#define LDS_BARRIER() asm volatile("s_waitcnt lgkmcnt(0)\n\ts_barrier" ::: "memory")

#if __has_builtin(__builtin_amdgcn_fdot2)
#define FDOT2(a, b, c) __builtin_amdgcn_fdot2((a), (b), (c), false)
#else
static __device__ inline float fdot2_fallback(half2v a, half2v b, float c) {
    return fmaf((float)a[1], (float)b[1], fmaf((float)a[0], (float)b[0], c));
}
#define FDOT2(a, b, c) fdot2_fallback((a), (b), (c))
#endif

// ---------------- Kernel 1: fused per-token table + Wh cast ----------------
__global__ __launch_bounds__(256) void precompute_k(
    const float* __restrict__ E, const float* __restrict__ Wx,
    const float* __restrict__ Wh, const float* __restrict__ Wz,
    float2* __restrict__ wgt, _Float16* __restrict__ Whf)
{
    const int v = blockIdx.x, e = threadIdx.x;
    __shared__ float Ev[256];
    Ev[e] = E[v * 256 + e];
    __syncthreads();
    float ax = 0.f, az = 0.f;
    #pragma unroll 4
    for (int d = 0; d < 256; d += 4) {
        float4 ev = *(const float4*)&Ev[d];
        float4 wx = *(const float4*)&Wx[e * 256 + d];
        float4 wz = *(const float4*)&Wz[e * 256 + d];
        ax += ev.x * wx.x + ev.y * wx.y + ev.z * wx.z + ev.w * wx.w;
        az += ev.x * wz.x + ev.y * wz.y + ev.z * wz.z + ev.w * wz.w;
    }
    float2 o; o.x = ax; o.y = 1.f / (1.f + __expf(-az));
    wgt[v * 256 + e] = o;
    Whf[v * 256 + e] = (_Float16)Wh[v * 256 + e];
}

// ---------------- Kernel 2: the serial recurrence (batch-per-WG dot2) -----
// 64 WGs x 1 batch, 256 threads (4 waves, 1/SIMD). Private barrier per batch
// -> independent chains never couple. Wave w owns output dims [64w, 64w+64).
// Lane l: g = l&15, kq = l>>4. Lane computes partial dots for dims
// dbase..dbase+3 over k in [64kq, 64kq+64) with v_dot2_f32_f16 against Wh
// rows held REGISTER-RESIDENT. Round-7 lesson: plain loads get SUNK into the
// step loop by the pressure heuristic (VGPR=84, L2 latency on the serial
// chain every step). Fix: asm-opacify each loaded value ("+v") so it cannot
// be rematerialized -> ~220 VGPRs live, still under the 512 cap at 1
// wave/SIMD (which is all we run anyway). 2-round __shfl_xor(16,32)
// completes the sums; each lane finishes dim dbase+kq: tanh epilogue, gated
// y-store, f16 h write to LDS (padded k-quarters -> conflict-free broadcast
// reads). One LDS-only barrier per step; wgt row gather prefetched 2 steps
// ahead directly into the consumed registers.
__global__ __launch_bounds__(256, 1) void rnn_k(
    const int* __restrict__ tokens, const float2* __restrict__ wgt,
    const _Float16* __restrict__ Whf, float* __restrict__ y)
{
    const int tid = threadIdx.x;
    const int w   = tid >> 6;                 // wave = output-dim chunk
    const int l   = tid & 63;
    const int g   = l & 15, kq = l >> 4;
    const int b   = blockIdx.x;               // global batch
    const int dbase = (w << 6) + (g << 2);    // first of 4 dims this lane dots
    const int k0    = kq << 6;                // k-range start (64 wide)
    const int dout  = dbase + kq;             // dim this lane finishes

    // Wh fragments in registers: wh8[j][c] = Wh[dbase+j][k0+8c .. k0+8c+7]
    // The empty asm with "+v" makes each value opaque: the compiler cannot
    // re-derive it from memory, so it MUST stay resident in VGPRs.
    half8 wh8[4][8];
    #pragma unroll
    for (int j = 0; j < 4; ++j)
        #pragma unroll
        for (int c = 0; c < 8; ++c) {
            wh8[j][c] = *(const half8*)(Whf + (dbase + j) * 256 + k0 + (c << 3));
            asm volatile("" : "+v"(wh8[j][c]));
        }

    // h double-buffered; k-quarters padded 64->72 f16 (144 B) so the 4 kq
    // broadcast-read groups land on disjoint banks.
    __shared__ __align__(16) _Float16 hb[2][4][72];
    __shared__ unsigned char tokL[T_LEN];

    for (int i = tid; i < T_LEN; i += 256)
        tokL[i] = (unsigned char)tokens[b * T_LEN + i];
    for (int i = tid; i < 2 * 4 * 72; i += 256) ((_Float16*)hb)[i] = (_Float16)0.f;
    LDS_BARRIER();

    // y byte offset: ((b*T + t)*256 + dout)*4, advances 1024 B per step
    unsigned int yoff = (unsigned)(b * (T_LEN * 256) + dout) * 4u;

    // prologue: wx/gate for t=0 (even regs) and t=1 (odd regs)
    float wx_e, g_e, wx_o, g_o;
    {
        const int t0 = tokL[0], t1 = tokL[1];
        float2 a = wgt[t0 * 256 + dout]; wx_e = a.x; g_e = a.y;
        float2 c = wgt[t1 * 256 + dout]; wx_o = c.x; g_o = c.y;
    }

// one k-pair (literal lane indices I0,I1 of the half8) against all 4 dims
#define DOT_P(cc, I0, I1)                                                      \
        {                                                                      \
            half2v hp = __builtin_shufflevector(hv, hv, I0, I1);               \
            ac0 = FDOT2(__builtin_shufflevector(wh8[0][cc], wh8[0][cc], I0, I1), hp, ac0); \
            ac1 = FDOT2(__builtin_shufflevector(wh8[1][cc], wh8[1][cc], I0, I1), hp, ac1); \
            ac2 = FDOT2(__builtin_shufflevector(wh8[2][cc], wh8[2][cc], I0, I1), hp, ac2); \
            ac3 = FDOT2(__builtin_shufflevector(wh8[3][cc], wh8[3][cc], I0, I1), hp, ac3); \
        }

// One timestep. Reads hb[CUR] (h_{t-1}), writes hb[NXT] (h_t). Consumes WX/G,
// then refills them IN PLACE for tcur+2 (first consumer two barriers later
// -> L2 gather latency fully covered).
#define STEP(tcur, CUR, NXT, WX, G)                                            \
    {                                                                          \
        int tf = (tcur) + 2; if (tf > T_LEN - 1) tf = T_LEN - 1;               \
        const int tok = tokL[tf];                                              \
        float ac0 = 0.f, ac1 = 0.f, ac2 = 0.f, ac3 = 0.f;                      \
        _Pragma("unroll")                                                      \
        for (int c = 0; c < 8; ++c) {                                          \
            half8 hv = *(const half8*)&hb[CUR][kq][c << 3];                    \
            DOT_P(c, 0, 1) DOT_P(c, 2, 3) DOT_P(c, 4, 5) DOT_P(c, 6, 7)        \
        }                                                                      \
        ac0 += __shfl_xor(ac0, 16); ac0 += __shfl_xor(ac0, 32);                \
        ac1 += __shfl_xor(ac1, 16); ac1 += __shfl_xor(ac1, 32);                \
        ac2 += __shfl_xor(ac2, 16); ac2 += __shfl_xor(ac2, 32);                \
        ac3 += __shfl_xor(ac3, 16); ac3 += __shfl_xor(ac3, 32);                \
        float s01 = (kq & 1) ? ac1 : ac0;                                      \
        float s23 = (kq & 1) ? ac3 : ac2;                                      \
        float sv  = (kq & 2) ? s23 : s01;                                      \
        float pre = sv + WX;                                                   \
        float ex  = __builtin_amdgcn_exp2f(pre * 2.885390082f);                \
        float hval = fmaf(__builtin_amdgcn_rcpf(ex + 1.f), -2.f, 1.f);         \
        __builtin_nontemporal_store(hval * G, (float*)((char*)y + yoff));      \
        yoff += 1024;                                                          \
        hb[NXT][w][(g << 2) + kq] = (_Float16)hval;                            \
        { const float2* gp = wgt + tok * 256 + dout; float2 a = *gp;           \
          WX = a.x; G = a.y; }                                                 \
        LDS_BARRIER();                                                         \
    }

    for (int t = 0; t < T_LEN; t += 2) {
        STEP(t,     0, 1, wx_e, g_e)   // even: h_{t-1} in buf0, h_t -> buf1
        STEP(t + 1, 1, 0, wx_o, g_o)   // odd:  h_t in buf1, h_{t+1} -> buf0
    }
#undef STEP
#undef DOT_P
}

// ---------------- Kernel 3: tied head, in place ----------------
__device__ inline half8 cvt8(const float* p) {
    float4 u = *(const float4*)p;
    float4 w = *(const float4*)(p + 4);
    half8 r;
    r[0] = (_Float16)u.x; r[1] = (_Float16)u.y; r[2] = (_Float16)u.z; r[3] = (_Float16)u.w;
    r[4] = (_Float16)w.x; r[5] = (_Float16)w.y; r[6] = (_Float16)w.z; r[7] = (_Float16)w.w;
    return r;
}

__global__ __launch_bounds__(256) void logits_k(
    const float* __restrict__ E, float* __restrict__ io)
{
    const int tid = threadIdx.x;
    const int wv = tid >> 6;             // v-chunk base = wv*64
    const int l  = tid & 63;
    const int n  = l & 15, q = l >> 4;
    const int rowbase = blockIdx.x << 6; // 64 rows per WG
    const int k0base = q << 3;

    floatx4 acc[4][4];
    #pragma unroll
    for (int mt = 0; mt < 4; ++mt)
        #pragma unroll
        for (int tn = 0; tn < 4; ++tn) acc[mt][tn] = 0.f;

    #pragma unroll
    for (int ks = 0; ks < 8; ++ks) {
        const int k0 = (ks << 5) + k0base;
        half8 a[4], bfr[4];
        #pragma unroll
        for (int mt = 0; mt < 4; ++mt)
            a[mt] = cvt8(io + (rowbase + (mt << 4) + n) * 256 + k0);
        #pragma unroll
        for (int tn = 0; tn < 4; ++tn)
            bfr[tn] = cvt8(E + ((wv << 6) + (tn << 4) + n) * 256 + k0);
        #pragma unroll
        for (int mt = 0; mt < 4; ++mt)
            #pragma unroll
            for (int tn = 0; tn < 4; ++tn)
                acc[mt][tn] = __builtin_amdgcn_mfma_f32_16x16x32_f16(a[mt], bfr[tn], acc[mt][tn], 0, 0, 0);
    }
    __syncthreads();  // every wave's y reads complete before anyone overwrites
    #pragma unroll
    for (int mt = 0; mt < 4; ++mt)
        #pragma unroll
        for (int tn = 0; tn < 4; ++tn)
            #pragma unroll
            for (int r = 0; r < 4; ++r)
                io[(rowbase + (mt << 4) + (q << 2) + r) * 256 + (wv << 6) + (tn << 4) + n] = acc[mt][tn][r];
}

// ---------------- host ----------------
extern "C" void kernel_launch(void* const* d_in, const int* in_sizes, int n_in,
                              void* d_out, int out_size, void* d_ws, size_t ws_size,
                              hipStream_t stream) {
    const int*   tokens = (const int*)d_in[0];
    const float* E      = (const float*)d_in[1];
    const float* Wx     = (const float*)d_in[2];
    const float* Wh     = (const float*)d_in[3];
    const float* Wz     = (const float*)d_in[4];
    float* out = (float*)d_out;

    char* ws = (char*)d_ws;
    float2*   wgt = (float2*)ws;                      // 512 KiB
    _Float16* Whf = (_Float16*)(ws + (512 << 10));    // 128 KiB

    precompute_k<<<256, 256, 0, stream>>>(E, Wx, Wh, Wz, wgt, Whf);
    rnn_k<<<64, 256, 0, stream>>>(tokens, wgt, Whf, out);
    logits_k<<<2048, 256, 0, stream>>>(E, out);
}